// Round 3
// baseline (133.111 us; speedup 1.0000x reference)
//
#include <hip/hip_runtime.h>
#include <math.h>

// DbrxRouter on MI355X:
//   logits = x[8192,6144] @ W^T[6144,16]; softmax; top-4; p=1 renorm.
//   Renorm cancels the softmax denominator -> only top-4 logits needed.
// R2 lesson (rule #20): butterfly loop with `break` left runtime acc[] indices
// -> acc[64] demoted to scratch (WRITE_SIZE=129MB == 524K threads x 256B).
// Fix: fully static 6-step reduce-scatter (macro, constexpr bounds) + W staged
// 4 experts at a time to keep live regs ~112 < 128 cap.

constexpr int H       = 6144;
constexpr int HQ      = H / 4;     // per-wave H range (1536 floats)
constexpr int TPB     = 256;       // 4 waves
constexpr int TOK_PB  = 4;         // tokens per block (all 4 waves cooperate)
constexpr int T_TOTAL = 8192;

__global__ __launch_bounds__(TPB, 4)
void dbrx_router(const float* __restrict__ x,
                 const float* __restrict__ w,
                 float* __restrict__ out)
{
    __shared__ float lds[4 * 64];     // [wave][token*16+expert] partial logits

    const int tid  = threadIdx.x;
    const int wave = tid >> 6;
    const int lane = tid & 63;

    const int tok0 = blockIdx.x * TOK_PB;
    const float* xb = x + (size_t)tok0 * H + wave * HQ + lane * 4;
    const float* wb = w + wave * HQ + lane * 4;

    // acc[t*16+e]: per-lane partial logits, 4 tokens x 16 experts = 64 regs
    float acc[64];
    #pragma unroll
    for (int i = 0; i < 64; ++i) acc[i] = 0.f;

    // Each iteration the wave covers 256 contiguous floats (float4/lane).
    #pragma unroll
    for (int i = 0; i < HQ / 256; ++i) {          // 6 iterations
        float4 xv[4];
        #pragma unroll
        for (int t = 0; t < 4; ++t)
            xv[t] = *reinterpret_cast<const float4*>(xb + (size_t)t * H + i * 256);

        #pragma unroll
        for (int eb = 0; eb < 4; ++eb) {          // experts in four blocks of 4
            float4 wv[4];
            #pragma unroll
            for (int e = 0; e < 4; ++e)
                wv[e] = *reinterpret_cast<const float4*>(wb + (size_t)(eb * 4 + e) * H + i * 256);

            #pragma unroll
            for (int t = 0; t < 4; ++t) {
                #pragma unroll
                for (int e = 0; e < 4; ++e) {
                    float s = acc[t * 16 + eb * 4 + e];
                    s = fmaf(xv[t].x, wv[e].x, s);
                    s = fmaf(xv[t].y, wv[e].y, s);
                    s = fmaf(xv[t].z, wv[e].z, s);
                    s = fmaf(xv[t].w, wv[e].w, s);
                    acc[t * 16 + eb * 4 + e] = s;
                }
            }
        }
    }

    // Butterfly reduce-scatter: 64 partials -> lane l holds fully-reduced
    // acc[l]. FULLY STATIC: constexpr bounds, no break, all indices
    // compile-time (rule #20 — runtime-indexed arrays go to scratch).
#define RSTEP(S) do {                                                  \
        constexpr int HN = 32 >> (S);   /* half size == xor mask */    \
        const bool hi = (lane & HN) != 0;                              \
        _Pragma("unroll")                                              \
        for (int i = 0; i < HN; ++i) {                                 \
            float send = hi ? acc[i] : acc[i + HN];                    \
            float keep = hi ? acc[i + HN] : acc[i];                    \
            float recv = __shfl_xor(send, HN, 64);                     \
            acc[i] = keep + recv;                                      \
        }                                                              \
    } while (0)
    RSTEP(0); RSTEP(1); RSTEP(2); RSTEP(3); RSTEP(4); RSTEP(5);
#undef RSTEP

    lds[wave * 64 + lane] = acc[0];
    __syncthreads();

    // One thread per token: combine the 4 H-quarters, top-4 (strict > ==
    // lowest-index tie-break, matching np/jax), renormalized exp weights.
    if (tid < TOK_PB) {
        float lg[16];
        #pragma unroll
        for (int e = 0; e < 16; ++e)
            lg[e] = lds[0 * 64 + tid * 16 + e] + lds[1 * 64 + tid * 16 + e]
                  + lds[2 * 64 + tid * 16 + e] + lds[3 * 64 + tid * 16 + e];

        float topv[4];
        int   topi[4];
        #pragma unroll
        for (int k = 0; k < 4; ++k) {
            float m = lg[0]; int mi = 0;
            #pragma unroll
            for (int e = 1; e < 16; ++e)
                if (lg[e] > m) { m = lg[e]; mi = e; }
            topv[k] = m; topi[k] = mi;
            #pragma unroll
            for (int e = 0; e < 16; ++e)          // static-index mask-out
                if (e == mi) lg[e] = -INFINITY;
        }

        float ex[4]; float sum = 0.f;
        #pragma unroll
        for (int k = 0; k < 4; ++k) { ex[k] = __expf(topv[k] - topv[0]); sum += ex[k]; }
        const float inv = 1.0f / sum;

        const int tok = tok0 + tid;
        #pragma unroll
        for (int k = 0; k < 4; ++k) {
            out[(size_t)tok * 4 + k] = ex[k] * inv;                          // top_weights
            out[(size_t)T_TOTAL * 4 + (size_t)tok * 4 + k] = (float)topi[k]; // top_experts
        }
    }
}

extern "C" void kernel_launch(void* const* d_in, const int* in_sizes, int n_in,
                              void* d_out, int out_size, void* d_ws, size_t ws_size,
                              hipStream_t stream) {
    const float* x = (const float*)d_in[0];   // hidden_states [4,2048,6144] fp32
    const float* w = (const float*)d_in[1];   // router_weight [16,6144] fp32
    float* out     = (float*)d_out;           // [8192*4 weights][8192*4 expert ids]
    dbrx_router<<<T_TOTAL / TOK_PB, TPB, 0, stream>>>(x, w, out);
}

// Round 4
// 69.839 us; speedup vs baseline: 1.9060x; 1.9060x over previous
//
#include <hip/hip_runtime.h>
#include <math.h>

// DbrxRouter on MI355X:
//   logits = x[8192,6144] @ W^T[6144,16]; softmax; top-4; p=1 renorm.
//   Renorm cancels the softmax denominator -> only top-4 logits needed.
//
// R2/R3 lesson: __launch_bounds__(256,4) made the allocator cap at 64 VGPRs
// and spill acc[] to scratch (WRITE_SIZE 129-156 MB vs 256 KB real output).
// R1 at (256,2) allocated 124 VGPRs with ZERO memory spill. So: keep the
// R3 geometry (grid=2048, acc[64], 4 tok/block) but relax the bound to
// (256,2) and moderate the H-loop unroll.

constexpr int H       = 6144;
constexpr int HQ      = H / 4;     // per-wave H range (1536 floats)
constexpr int TPB     = 256;       // 4 waves
constexpr int TOK_PB  = 4;         // tokens per block (all 4 waves cooperate)
constexpr int T_TOTAL = 8192;

__global__ __launch_bounds__(TPB, 2)
void dbrx_router(const float* __restrict__ x,
                 const float* __restrict__ w,
                 float* __restrict__ out)
{
    __shared__ float lds[4 * 64];     // [wave][token*16+expert] partial logits

    const int tid  = threadIdx.x;
    const int wave = tid >> 6;
    const int lane = tid & 63;

    const int tok0 = blockIdx.x * TOK_PB;
    const float* xb = x + (size_t)tok0 * H + wave * HQ + lane * 4;
    const float* wb = w + wave * HQ + lane * 4;

    // acc[t*16+e]: per-lane partial logits, 4 tokens x 16 experts = 64 regs
    float acc[64];
    #pragma unroll
    for (int i = 0; i < 64; ++i) acc[i] = 0.f;

    // Each iteration the wave covers 256 contiguous floats (float4/lane).
    // unroll 2 (R1's known-good setting) keeps address/load pressure bounded.
    #pragma unroll 2
    for (int i = 0; i < HQ / 256; ++i) {          // 6 iterations
        float4 xv[4];
        #pragma unroll
        for (int t = 0; t < 4; ++t)
            xv[t] = *reinterpret_cast<const float4*>(xb + (size_t)t * H + i * 256);

        #pragma unroll
        for (int eb = 0; eb < 4; ++eb) {          // experts in four blocks of 4
            float4 wv[4];
            #pragma unroll
            for (int e = 0; e < 4; ++e)
                wv[e] = *reinterpret_cast<const float4*>(wb + (size_t)(eb * 4 + e) * H + i * 256);

            #pragma unroll
            for (int t = 0; t < 4; ++t) {
                #pragma unroll
                for (int e = 0; e < 4; ++e) {
                    float s = acc[t * 16 + eb * 4 + e];
                    s = fmaf(xv[t].x, wv[e].x, s);
                    s = fmaf(xv[t].y, wv[e].y, s);
                    s = fmaf(xv[t].z, wv[e].z, s);
                    s = fmaf(xv[t].w, wv[e].w, s);
                    acc[t * 16 + eb * 4 + e] = s;
                }
            }
        }
    }

    // Butterfly reduce-scatter: 64 partials -> lane l holds fully-reduced
    // acc[l]. Fully static: constexpr bounds, all indices compile-time.
#define RSTEP(S) do {                                                  \
        constexpr int HN = 32 >> (S);   /* half size == xor mask */    \
        const bool hi = (lane & HN) != 0;                              \
        _Pragma("unroll")                                              \
        for (int i = 0; i < HN; ++i) {                                 \
            float send = hi ? acc[i] : acc[i + HN];                    \
            float keep = hi ? acc[i + HN] : acc[i];                    \
            float recv = __shfl_xor(send, HN, 64);                     \
            acc[i] = keep + recv;                                      \
        }                                                              \
    } while (0)
    RSTEP(0); RSTEP(1); RSTEP(2); RSTEP(3); RSTEP(4); RSTEP(5);
#undef RSTEP

    lds[wave * 64 + lane] = acc[0];
    __syncthreads();

    // One thread per token: combine the 4 H-quarters, top-4 (strict > ==
    // lowest-index tie-break, matching np/jax), renormalized exp weights.
    if (tid < TOK_PB) {
        float lg[16];
        #pragma unroll
        for (int e = 0; e < 16; ++e)
            lg[e] = lds[0 * 64 + tid * 16 + e] + lds[1 * 64 + tid * 16 + e]
                  + lds[2 * 64 + tid * 16 + e] + lds[3 * 64 + tid * 16 + e];

        float topv[4];
        int   topi[4];
        #pragma unroll
        for (int k = 0; k < 4; ++k) {
            float m = lg[0]; int mi = 0;
            #pragma unroll
            for (int e = 1; e < 16; ++e)
                if (lg[e] > m) { m = lg[e]; mi = e; }
            topv[k] = m; topi[k] = mi;
            #pragma unroll
            for (int e = 0; e < 16; ++e)          // static-index mask-out
                if (e == mi) lg[e] = -INFINITY;
        }

        float ex[4]; float sum = 0.f;
        #pragma unroll
        for (int k = 0; k < 4; ++k) { ex[k] = __expf(topv[k] - topv[0]); sum += ex[k]; }
        const float inv = 1.0f / sum;

        const int tok = tok0 + tid;
        #pragma unroll
        for (int k = 0; k < 4; ++k) {
            out[(size_t)tok * 4 + k] = ex[k] * inv;                          // top_weights
            out[(size_t)T_TOTAL * 4 + (size_t)tok * 4 + k] = (float)topi[k]; // top_experts
        }
    }
}

extern "C" void kernel_launch(void* const* d_in, const int* in_sizes, int n_in,
                              void* d_out, int out_size, void* d_ws, size_t ws_size,
                              hipStream_t stream) {
    const float* x = (const float*)d_in[0];   // hidden_states [4,2048,6144] fp32
    const float* w = (const float*)d_in[1];   // router_weight [16,6144] fp32
    float* out     = (float*)d_out;           // [8192*4 weights][8192*4 expert ids]
    dbrx_router<<<T_TOTAL / TOK_PB, TPB, 0, stream>>>(x, w, out);
}